// Round 1
// 340.758 us; speedup vs baseline: 1.0452x; 1.0452x over previous
//
#include <hip/hip_runtime.h>
#include <hip/hip_bf16.h>
#include <math.h>

typedef __bf16 bf16;
typedef __attribute__((ext_vector_type(8))) __bf16 bf16x8;
typedef __attribute__((ext_vector_type(4))) __bf16 bf16x4;
typedef __attribute__((ext_vector_type(4))) short short4v;
typedef __attribute__((ext_vector_type(4))) float f32x4;

#define MFMA16(a,b,c)  __builtin_amdgcn_mfma_f32_16x16x32_bf16((a),(b),(c),0,0,0)
#define MFMAK16(a,b,c) __builtin_amdgcn_mfma_f32_16x16x16bf16_1k((a),(b),(c),0,0,0)

__device__ __forceinline__ void gload16(const void* gp, void* lp) {
  __builtin_amdgcn_global_load_lds(
      (const __attribute__((address_space(1))) void*)gp,
      (__attribute__((address_space(3))) void*)lp, 16, 0, 0);
}

// ---------------- x cast: fp32 -> bf16, 8 elems/thread ----------------
__global__ __launch_bounds__(256) void cast_x(
    const float* __restrict__ x, bf16* __restrict__ xb)
{
  size_t i = ((size_t)blockIdx.x*256 + threadIdx.x) * 8;
  f32x4 a = *(const f32x4*)(x+i);
  f32x4 b = *(const f32x4*)(x+i+4);
  bf16x8 o;
  #pragma unroll
  for (int j=0;j<4;j++) { o[j] = (bf16)a[j]; o[4+j] = (bf16)b[j]; }
  *(bf16x8*)(xb+i) = o;
}

// ---------------- transpose+cast: Wt[n][k] (bf16) = W[k][n] (fp32), up to 3 mats --------
__global__ __launch_bounds__(1024) void tr_cast(
    const float* __restrict__ w0, const float* __restrict__ w1,
    const float* __restrict__ w2, bf16* __restrict__ dst)
{
  __shared__ bf16 tile[64][65];
  const float* src = (blockIdx.z==0)?w0:(blockIdx.z==1)?w1:w2;
  bf16* d = dst + (size_t)blockIdx.z * (1024*1024);
  int x = threadIdx.x, y = threadIdx.y;
  int tc = blockIdx.x, tr = blockIdx.y;
  #pragma unroll
  for (int i=0;i<4;i++) {
    int r = y + i*16;
    tile[r][x] = (bf16)src[(size_t)(tr*64+r)*1024 + tc*64 + x];
  }
  __syncthreads();
  #pragma unroll
  for (int i=0;i<4;i++) {
    int r = y + i*16;
    d[(size_t)(tc*64+r)*1024 + tr*64 + x] = tile[x][r];
  }
}

// ---------------- fused QKV GEMM, pure gload16 staging (m97 path) ----------------
// [q|k|v] = xb @ [WqT|WkT|WvT]^T + b.  A bf16, Bt bf16, N=3072.
// q output is PRE-SCALED by 1/sqrt(Hd)*log2(e) so attn's softmax needs no per-element mul.
__global__ __launch_bounds__(256) void gemm_qkv(
    const bf16* __restrict__ A, const bf16* __restrict__ Bt,
    const float* __restrict__ bq, const float* __restrict__ bk, const float* __restrict__ bv,
    bf16* __restrict__ q, bf16* __restrict__ k, bf16* __restrict__ v,
    int M, int K)
{
  __shared__ __align__(16) bf16 As[128*32];
  __shared__ __align__(16) bf16 Bs[128*32];
  const int tid  = threadIdx.x;
  const int wave = tid >> 6;
  const int lane = tid & 63;
  const int l15  = lane & 15;
  const int quad = lane >> 4;
  const int m0 = blockIdx.y * 128;
  const int n0 = blockIdx.x * 128;
  const int wm = (wave >> 1) * 64;
  const int wn = (wave & 1) * 64;
  const int srow = lane >> 2;
  const int scol = (lane & 3) * 8;

  f32x4 acc[4][4];
  #pragma unroll
  for (int i=0;i<4;i++)
    #pragma unroll
    for (int j=0;j<4;j++)
      acc[i][j] = (f32x4){0.f,0.f,0.f,0.f};

  for (int k0 = 0; k0 < K; k0 += 32) {
    __syncthreads();
    #pragma unroll
    for (int p=0;p<2;p++) {
      int c = p*4 + wave;
      int row = c*16 + srow;
      gload16(A  + (size_t)(m0+row)*K + k0 + scol, As + c*512);
      gload16(Bt + (size_t)(n0+row)*K + k0 + scol, Bs + c*512);
    }
    __syncthreads();
    bf16x8 af[4], bfr[4];
    #pragma unroll
    for (int t=0;t<4;t++) {
      af[t]  = *(const bf16x8*)(As + (wm + t*16 + l15)*32 + quad*8);
      bfr[t] = *(const bf16x8*)(Bs + (wn + t*16 + l15)*32 + quad*8);
    }
    #pragma unroll
    for (int mt=0;mt<4;mt++)
      #pragma unroll
      for (int nt=0;nt<4;nt++)
        acc[mt][nt] = MFMA16(af[mt], bfr[nt], acc[mt][nt]);
  }

  const int mat = n0 >> 10;
  const float* bsel = (mat==0) ? bq : (mat==1) ? bk : bv;
  bf16*       osel  = (mat==0) ? q  : (mat==1) ? k  : v;
  const float qsc   = (mat==0) ? 0.1803368801f : 1.0f;  // log2(e)/sqrt(64)
  #pragma unroll
  for (int nt=0;nt<4;nt++) {
    int col = n0 + wn + nt*16 + l15;
    int cw  = col & 1023;
    float bvv = bsel[cw];
    #pragma unroll
    for (int mt=0;mt<4;mt++) {
      int row = m0 + wm + mt*16 + quad*4;
      #pragma unroll
      for (int r=0;r<4;r++)
        osel[(size_t)(row + r)*1024 + cw] = (bf16)((acc[mt][nt][r] + bvv) * qsc);
    }
  }
}

// ---------------- final GEMM: out(fp32) = ao(bf16) @ WtO^T + bo ----------------
__global__ __launch_bounds__(256) void gemm_out(
    const bf16* __restrict__ A, const bf16* __restrict__ Bt,
    const float* __restrict__ bias, float* __restrict__ C,
    int M, int N, int K)
{
  __shared__ __align__(16) bf16 As[128*32];
  __shared__ __align__(16) bf16 Bs[128*32];
  const int tid  = threadIdx.x;
  const int wave = tid >> 6;
  const int lane = tid & 63;
  const int l15  = lane & 15;
  const int quad = lane >> 4;
  const int m0 = blockIdx.y * 128;
  const int n0 = blockIdx.x * 128;
  const int wm = (wave >> 1) * 64;
  const int wn = (wave & 1) * 64;
  const int srow = lane >> 2;
  const int scol = (lane & 3) * 8;

  f32x4 acc[4][4];
  #pragma unroll
  for (int i=0;i<4;i++)
    #pragma unroll
    for (int j=0;j<4;j++)
      acc[i][j] = (f32x4){0.f,0.f,0.f,0.f};

  for (int k0 = 0; k0 < K; k0 += 32) {
    __syncthreads();
    #pragma unroll
    for (int p=0;p<2;p++) {
      int c = p*4 + wave;
      int row = c*16 + srow;
      gload16(A  + (size_t)(m0+row)*K + k0 + scol, As + c*512);
      gload16(Bt + (size_t)(n0+row)*K + k0 + scol, Bs + c*512);
    }
    __syncthreads();
    bf16x8 af[4], bfr[4];
    #pragma unroll
    for (int t=0;t<4;t++) {
      af[t]  = *(const bf16x8*)(As + (wm + t*16 + l15)*32 + quad*8);
      bfr[t] = *(const bf16x8*)(Bs + (wn + t*16 + l15)*32 + quad*8);
    }
    #pragma unroll
    for (int mt=0;mt<4;mt++)
      #pragma unroll
      for (int nt=0;nt<4;nt++)
        acc[mt][nt] = MFMA16(af[mt], bfr[nt], acc[mt][nt]);
  }

  #pragma unroll
  for (int nt=0;nt<4;nt++) {
    int col = n0 + wn + nt*16 + l15;
    float bvv = bias[col];
    #pragma unroll
    for (int mt=0;mt<4;mt++) {
      int row = m0 + wm + mt*16 + quad*4;
      #pragma unroll
      for (int r=0;r<4;r++)
        C[(size_t)(row + r)*N + col] = acc[mt][nt][r] + bvv;
    }
  }
}

// ---------------- flash attention, S^T formulation ----------------
// Changes vs r7: (1) unpadded [64][128B] LDS tiles with XOR swizzle
//   Ks: byte ^= (t&7)<<4  (16B granularity, b128 reads stay aligned)
//   Vt: byte ^= (d&15)<<3 (8B granularity, b64 reads stay aligned)
//   -> PV ds_read_b64 conflict-free; LDS 36864->32768 B = 5 blocks/CU.
// (2) Q arrives pre-scaled (gemm_qkv) -> no per-element softmax mul.
// (3) native v_exp_f32 via __builtin_amdgcn_exp2f.
// (4) s_setprio(1) around MFMA clusters (m191: attn-applicable).
// O may alias Q: each (b,row,h-slice) is read-at-start / written-at-end by exactly
// one block, so in-place is race-free.
__global__ __launch_bounds__(256, 5) void attn_fwd(
    const bf16* __restrict__ Q, const bf16* __restrict__ Kp,
    const bf16* __restrict__ V, bf16* __restrict__ O)
{
  __shared__ __align__(16) char KsB[2*8192];  // [buf][t][d-bytes ^ ((t&7)<<4)]
  __shared__ __align__(16) char VtB[2*8192];  // [buf][d][t-bytes ^ ((d&15)<<3)]

  const int tid  = threadIdx.x;
  const int w    = tid >> 6;
  const int lane = tid & 63;
  const int l15  = lane & 15;
  const int quad = lane >> 4;

  const int bid = blockIdx.x;
  const int qt  = 63 - (bid >> 5);   // descending work order
  const int bh  = bid & 31;
  const int h   = bh & 15;
  const int b   = bh >> 4;

  const size_t headoff = (size_t)h * 64;
  const size_t bbase   = (size_t)b * 4096;

  bf16x8 aq[2];
  {
    int row = qt*64 + w*16 + l15;
    const bf16* qp = Q + (bbase + row)*1024 + headoff + quad*8;
    aq[0] = *(const bf16x8*)(qp);
    aq[1] = *(const bf16x8*)(qp + 32);
  }

  short4v ones_s;
  {
    bf16x4 o1;
    #pragma unroll
    for (int j=0;j<4;j++) o1[j] = (bf16)1.0f;
    ones_s = __builtin_bit_cast(short4v, o1);
  }

  f32x4 acco[4];
  f32x4 accli;
  #pragma unroll
  for (int i=0;i<4;i++) acco[i] = (f32x4){0.f,0.f,0.f,0.f};
  accli = (f32x4){0.f,0.f,0.f,0.f};

  // ---- staging geometry (byte offsets, hoisted once) ----
  const int kt_row = tid >> 2;
  const int kswz   = (kt_row & 7) << 4;
  const int ks_w0  = kt_row*128 + (((tid & 3)*32)      ^ kswz);
  const int ks_w1  = kt_row*128 + (((tid & 3)*32 + 16) ^ kswz);
  const int vt_wbase = w*2048;     // d = w*16 + j  ->  d*128 = w*2048 + j*128
  const int vt_wlane = 2*lane;     // t = lane      ->  2t, XOR'd with (d&15)<<3 per j

  // ---- read geometry (XOR decomposed into per-lane base + compile-time imm) ----
  // Ks read:  addr = tt*2048 + l15*128 + ((quad^(s7&3))<<4) + ((kk^(s7>>2))<<6)
  const int s7    = l15 & 7;
  const int ks_r0 = l15*128 + ((quad ^ (s7 & 3)) << 4) + ((s7 >> 2) << 6);
  const int ks_r1 = ks_r0 ^ 64;
  // Vt read:  addr = nt*2048 + l15*128 + ((quad^(l15&3))<<3) + ((tt^(l15>>2))<<5)
  const int vt_rbase = l15*128 + ((quad ^ (l15 & 3)) << 3) + ((l15 >> 2) << 5);
  int vt_r[4];
  #pragma unroll
  for (int tt=0;tt<4;tt++) vt_r[tt] = vt_rbase ^ (tt << 5);

  {
    const bf16* kp = Kp + (bbase + kt_row)*1024 + headoff + (tid & 3)*16;
    bf16x8 k0 = *(const bf16x8*)(kp);
    bf16x8 k1 = *(const bf16x8*)(kp + 8);
    *(bf16x8*)(KsB + ks_w0) = k0;
    *(bf16x8*)(KsB + ks_w1) = k1;
    const bf16* vp = V + (bbase + lane)*1024 + headoff + w*16;
    bf16x8 v0 = *(const bf16x8*)(vp);
    bf16x8 v1 = *(const bf16x8*)(vp + 8);
    #pragma unroll
    for (int j=0;j<8;j++) {
      *(bf16*)(VtB + vt_wbase + j*128     + (vt_wlane ^ (j<<3)))     = v0[j];
      *(bf16*)(VtB + vt_wbase + (8+j)*128 + (vt_wlane ^ ((8+j)<<3))) = v1[j];
    }
  }
  __syncthreads();

  const bf16* kpref = Kp + (bbase + 64 + kt_row)*1024 + headoff + (tid & 3)*16;
  const bf16* vpref = V  + (bbase + 64 + lane)*1024 + headoff + w*16;

  for (int kt = 0; kt <= qt; ++kt) {
    const int p = kt & 1;
    const bool pre = (kt < qt);

    bf16x8 kr0, kr1, vr0, vr1;
    if (pre) {
      kr0 = *(const bf16x8*)(kpref);
      kr1 = *(const bf16x8*)(kpref + 8);
      vr0 = *(const bf16x8*)(vpref);
      vr1 = *(const bf16x8*)(vpref + 8);
      kpref += 64*1024;
      vpref += 64*1024;
    }

    const char* ksb = KsB + p*8192;
    const char* vtb = VtB + p*8192;

    f32x4 accs[4];
    #pragma unroll
    for (int i=0;i<4;i++) accs[i] = (f32x4){0.f,0.f,0.f,0.f};

    __builtin_amdgcn_s_setprio(1);
    #pragma unroll
    for (int kk=0;kk<2;kk++) {
      #pragma unroll
      for (int tt=0;tt<4;tt++) {
        bf16x8 ka = *(const bf16x8*)(ksb + (kk ? ks_r1 : ks_r0) + tt*2048);
        accs[tt] = MFMA16(ka, aq[kk], accs[tt]);
      }
    }
    __builtin_amdgcn_s_setprio(0);

    const bool diag = (kt == qt);
    short4v pts[4];
    #pragma unroll
    for (int tt=0;tt<4;tt++) {
      bf16x4 pb;
      #pragma unroll
      for (int r=0;r<4;r++) {
        float tv = fminf(accs[tt][r], 60.0f);          // accs already scaled (q pre-scaled)
        float pf = __builtin_amdgcn_exp2f(tv);
        if (diag && (tt*16 + quad*4 + r > w*16 + l15)) pf = 0.0f;
        pb[r] = (bf16)pf;
      }
      pts[tt] = __builtin_bit_cast(short4v, pb);
    }

    __builtin_amdgcn_s_setprio(1);
    #pragma unroll
    for (int nt=0;nt<4;nt++) {
      #pragma unroll
      for (int tt=0;tt<4;tt++) {
        bf16x4 va = *(const bf16x4*)(vtb + vt_r[tt] + nt*2048);
        acco[nt] = MFMAK16(__builtin_bit_cast(short4v, va), pts[tt], acco[nt]);
      }
    }
    #pragma unroll
    for (int tt=0;tt<4;tt++)
      accli = MFMAK16(ones_s, pts[tt], accli);
    __builtin_amdgcn_s_setprio(0);

    if (pre) {
      char* ksn = KsB + (p^1)*8192;
      char* vtn = VtB + (p^1)*8192;
      *(bf16x8*)(ksn + ks_w0) = kr0;
      *(bf16x8*)(ksn + ks_w1) = kr1;
      #pragma unroll
      for (int j=0;j<8;j++) {
        *(bf16*)(vtn + vt_wbase + j*128     + (vt_wlane ^ (j<<3)))     = vr0[j];
        *(bf16*)(vtn + vt_wbase + (8+j)*128 + (vt_wlane ^ ((8+j)<<3))) = vr1[j];
      }
      __syncthreads();
    }
  }

  {
    float inv = 1.0f / accli[0];
    int qrow = qt*64 + w*16 + l15;
    bf16* ob = O + (bbase + qrow)*1024 + headoff;
    #pragma unroll
    for (int nt=0;nt<4;nt++) {
      bf16x4 o;
      #pragma unroll
      for (int r=0;r<4;r++) o[r] = (bf16)(acco[nt][r] * inv);
      *(bf16x4*)(ob + nt*16 + quad*4) = o;
    }
  }
}

extern "C" void kernel_launch(void* const* d_in, const int* in_sizes, int n_in,
                              void* d_out, int out_size, void* d_ws, size_t ws_size,
                              hipStream_t stream) {
  const float* x  = (const float*)d_in[0];
  const float* Wq = (const float*)d_in[1];
  const float* bq = (const float*)d_in[2];
  const float* Wk = (const float*)d_in[3];
  const float* bk = (const float*)d_in[4];
  const float* Wv = (const float*)d_in[5];
  const float* bv = (const float*)d_in[6];
  const float* Wo = (const float*)d_in[7];
  const float* bo = (const float*)d_in[8];
  float* out = (float*)d_out;

  // ws (bf16 elems, 64 MB): q 8M | k 8M | v 8M | xb 8M.
  // ao written in-place over q (block-exclusive slices). WtO reuses xb after gemm_qkv.
  // WtQKV (3M el) lives in d_out scratch (fully overwritten by the final GEMM).
  bf16* ws = (bf16*)d_ws;
  bf16* q  = ws;
  bf16* k  = q + (size_t)8192*1024;
  bf16* v  = k + (size_t)8192*1024;
  bf16* xb = v + (size_t)8192*1024;
  bf16* ao = q;                      // in-place
  bf16* WtQKV = (bf16*)d_out;        // scratch: dead before gemm_out writes d_out
  bf16* WtO   = xb;                  // xb dead after gemm_qkv

  tr_cast<<<dim3(16,16,3), dim3(64,16), 0, stream>>>(Wq, Wk, Wv, WtQKV);
  cast_x<<<4096, 256, 0, stream>>>(x, xb);
  gemm_qkv<<<dim3(24,64), 256, 0, stream>>>(xb, WtQKV, bq, bk, bv, q, k, v, 8192, 1024);
  tr_cast<<<dim3(16,16,1), dim3(64,16), 0, stream>>>(Wo, Wo, Wo, WtO);
  attn_fwd<<<2048, 256, 0, stream>>>(q, k, v, ao);
  gemm_out<<<dim3(8,64), 256, 0, stream>>>(ao, WtO, bo, out, 8192, 1024, 1024);
}

// Round 2
// 334.733 us; speedup vs baseline: 1.0640x; 1.0180x over previous
//
#include <hip/hip_runtime.h>
#include <hip/hip_bf16.h>
#include <math.h>

typedef __bf16 bf16;
typedef __attribute__((ext_vector_type(8))) __bf16 bf16x8;
typedef __attribute__((ext_vector_type(4))) __bf16 bf16x4;
typedef __attribute__((ext_vector_type(4))) short short4v;
typedef __attribute__((ext_vector_type(4))) float f32x4;

#define MFMA16(a,b,c)  __builtin_amdgcn_mfma_f32_16x16x32_bf16((a),(b),(c),0,0,0)
#define MFMAK16(a,b,c) __builtin_amdgcn_mfma_f32_16x16x16bf16_1k((a),(b),(c),0,0,0)

__device__ __forceinline__ void gload16(const void* gp, void* lp) {
  __builtin_amdgcn_global_load_lds(
      (const __attribute__((address_space(1))) void*)gp,
      (__attribute__((address_space(3))) void*)lp, 16, 0, 0);
}

// ---------------- x cast: fp32 -> bf16, 8 elems/thread ----------------
__global__ __launch_bounds__(256) void cast_x(
    const float* __restrict__ x, bf16* __restrict__ xb)
{
  size_t i = ((size_t)blockIdx.x*256 + threadIdx.x) * 8;
  f32x4 a = *(const f32x4*)(x+i);
  f32x4 b = *(const f32x4*)(x+i+4);
  bf16x8 o;
  #pragma unroll
  for (int j=0;j<4;j++) { o[j] = (bf16)a[j]; o[4+j] = (bf16)b[j]; }
  *(bf16x8*)(xb+i) = o;
}

// ---------------- transpose+cast: Wt[n][k] (bf16) = W[k][n] (fp32), up to 3 mats --------
__global__ __launch_bounds__(1024) void tr_cast(
    const float* __restrict__ w0, const float* __restrict__ w1,
    const float* __restrict__ w2, bf16* __restrict__ dst)
{
  __shared__ bf16 tile[64][65];
  const float* src = (blockIdx.z==0)?w0:(blockIdx.z==1)?w1:w2;
  bf16* d = dst + (size_t)blockIdx.z * (1024*1024);
  int x = threadIdx.x, y = threadIdx.y;
  int tc = blockIdx.x, tr = blockIdx.y;
  #pragma unroll
  for (int i=0;i<4;i++) {
    int r = y + i*16;
    tile[r][x] = (bf16)src[(size_t)(tr*64+r)*1024 + tc*64 + x];
  }
  __syncthreads();
  #pragma unroll
  for (int i=0;i<4;i++) {
    int r = y + i*16;
    d[(size_t)(tc*64+r)*1024 + tr*64 + x] = tile[x][r];
  }
}

// ---------------- fused QKV GEMM, pure gload16 staging (m97 path) ----------------
// [q|k|v] = xb @ [WqT|WkT|WvT]^T + b.  A bf16, Bt bf16, N=3072.
// q output is PRE-SCALED by 1/sqrt(Hd)*log2(e) so attn's softmax needs no per-element mul.
// v output is written TRANSPOSED per head: vT[b][h][d][t] (contiguous bf16x4 in t)
// so attn can stage V into its transposed LDS tile with vector ops.
__global__ __launch_bounds__(256) void gemm_qkv(
    const bf16* __restrict__ A, const bf16* __restrict__ Bt,
    const float* __restrict__ bq, const float* __restrict__ bk, const float* __restrict__ bv,
    bf16* __restrict__ q, bf16* __restrict__ k, bf16* __restrict__ v,
    int M, int K)
{
  __shared__ __align__(16) bf16 As[128*32];
  __shared__ __align__(16) bf16 Bs[128*32];
  const int tid  = threadIdx.x;
  const int wave = tid >> 6;
  const int lane = tid & 63;
  const int l15  = lane & 15;
  const int quad = lane >> 4;
  const int m0 = blockIdx.y * 128;
  const int n0 = blockIdx.x * 128;
  const int wm = (wave >> 1) * 64;
  const int wn = (wave & 1) * 64;
  const int srow = lane >> 2;
  const int scol = (lane & 3) * 8;

  f32x4 acc[4][4];
  #pragma unroll
  for (int i=0;i<4;i++)
    #pragma unroll
    for (int j=0;j<4;j++)
      acc[i][j] = (f32x4){0.f,0.f,0.f,0.f};

  for (int k0 = 0; k0 < K; k0 += 32) {
    __syncthreads();
    #pragma unroll
    for (int p=0;p<2;p++) {
      int c = p*4 + wave;
      int row = c*16 + srow;
      gload16(A  + (size_t)(m0+row)*K + k0 + scol, As + c*512);
      gload16(Bt + (size_t)(n0+row)*K + k0 + scol, Bs + c*512);
    }
    __syncthreads();
    bf16x8 af[4], bfr[4];
    #pragma unroll
    for (int t=0;t<4;t++) {
      af[t]  = *(const bf16x8*)(As + (wm + t*16 + l15)*32 + quad*8);
      bfr[t] = *(const bf16x8*)(Bs + (wn + t*16 + l15)*32 + quad*8);
    }
    #pragma unroll
    for (int mt=0;mt<4;mt++)
      #pragma unroll
      for (int nt=0;nt<4;nt++)
        acc[mt][nt] = MFMA16(af[mt], bfr[nt], acc[mt][nt]);
  }

  const int mat = n0 >> 10;
  if (mat == 2) {
    // v: transposed per-head write, contiguous in t (4 tokens per store)
    #pragma unroll
    for (int nt=0;nt<4;nt++) {
      int col = (n0 & 1023) + wn + nt*16 + l15;
      int hh = col >> 6, dl = col & 63;
      float bvv = bv[col];
      #pragma unroll
      for (int mt=0;mt<4;mt++) {
        int row = m0 + wm + mt*16 + quad*4;
        int bb = row >> 12, tt = row & 4095;
        bf16x4 o;
        #pragma unroll
        for (int r=0;r<4;r++) o[r] = (bf16)(acc[mt][nt][r] + bvv);
        *(bf16x4*)(v + ((size_t)((bb*16 + hh)*64 + dl))*4096 + tt) = o;
      }
    }
  } else {
    const float* bsel = (mat==0) ? bq : bk;
    bf16*       osel  = (mat==0) ? q  : k;
    const float qsc   = (mat==0) ? 0.1803368801f : 1.0f;  // log2(e)/sqrt(64)
    #pragma unroll
    for (int nt=0;nt<4;nt++) {
      int col = n0 + wn + nt*16 + l15;
      int cw  = col & 1023;
      float bvv = bsel[cw];
      #pragma unroll
      for (int mt=0;mt<4;mt++) {
        int row = m0 + wm + mt*16 + quad*4;
        #pragma unroll
        for (int r=0;r<4;r++)
          osel[(size_t)(row + r)*1024 + cw] = (bf16)((acc[mt][nt][r] + bvv) * qsc);
      }
    }
  }
}

// ---------------- final GEMM: out(fp32) = ao(bf16) @ WtO^T + bo ----------------
__global__ __launch_bounds__(256) void gemm_out(
    const bf16* __restrict__ A, const bf16* __restrict__ Bt,
    const float* __restrict__ bias, float* __restrict__ C,
    int M, int N, int K)
{
  __shared__ __align__(16) bf16 As[128*32];
  __shared__ __align__(16) bf16 Bs[128*32];
  const int tid  = threadIdx.x;
  const int wave = tid >> 6;
  const int lane = tid & 63;
  const int l15  = lane & 15;
  const int quad = lane >> 4;
  const int m0 = blockIdx.y * 128;
  const int n0 = blockIdx.x * 128;
  const int wm = (wave >> 1) * 64;
  const int wn = (wave & 1) * 64;
  const int srow = lane >> 2;
  const int scol = (lane & 3) * 8;

  f32x4 acc[4][4];
  #pragma unroll
  for (int i=0;i<4;i++)
    #pragma unroll
    for (int j=0;j<4;j++)
      acc[i][j] = (f32x4){0.f,0.f,0.f,0.f};

  for (int k0 = 0; k0 < K; k0 += 32) {
    __syncthreads();
    #pragma unroll
    for (int p=0;p<2;p++) {
      int c = p*4 + wave;
      int row = c*16 + srow;
      gload16(A  + (size_t)(m0+row)*K + k0 + scol, As + c*512);
      gload16(Bt + (size_t)(n0+row)*K + k0 + scol, Bs + c*512);
    }
    __syncthreads();
    bf16x8 af[4], bfr[4];
    #pragma unroll
    for (int t=0;t<4;t++) {
      af[t]  = *(const bf16x8*)(As + (wm + t*16 + l15)*32 + quad*8);
      bfr[t] = *(const bf16x8*)(Bs + (wn + t*16 + l15)*32 + quad*8);
    }
    #pragma unroll
    for (int mt=0;mt<4;mt++)
      #pragma unroll
      for (int nt=0;nt<4;nt++)
        acc[mt][nt] = MFMA16(af[mt], bfr[nt], acc[mt][nt]);
  }

  #pragma unroll
  for (int nt=0;nt<4;nt++) {
    int col = n0 + wn + nt*16 + l15;
    float bvv = bias[col];
    #pragma unroll
    for (int mt=0;mt<4;mt++) {
      int row = m0 + wm + mt*16 + quad*4;
      #pragma unroll
      for (int r=0;r<4;r++)
        C[(size_t)(row + r)*N + col] = acc[mt][nt][r] + bvv;
    }
  }
}

// ---------------- flash attention, S^T formulation ----------------
// R2 change: V arrives pre-transposed (vT[b][h][d][t]) from gemm_qkv, so the
// V LDS staging is 2x global b128 + 4x ds_write_b64 into the XOR-swizzled
// [d][t] tile (conflict-free), replacing the 16x scalar-b16 scatter that was
// oversubscribing the LDS pipe.
// O may alias Q: each (b,row,h-slice) is read-at-start / written-at-end by exactly
// one block, so in-place is race-free.
__global__ __launch_bounds__(256, 5) void attn_fwd(
    const bf16* __restrict__ Q, const bf16* __restrict__ Kp,
    const bf16* __restrict__ Vt, bf16* __restrict__ O)
{
  __shared__ __align__(16) char KsB[2*8192];  // [buf][t][d-bytes ^ ((t&7)<<4)]
  __shared__ __align__(16) char VtB[2*8192];  // [buf][d][t-bytes ^ ((d&15)<<3)]

  const int tid  = threadIdx.x;
  const int w    = tid >> 6;
  const int lane = tid & 63;
  const int l15  = lane & 15;
  const int quad = lane >> 4;

  const int bid = blockIdx.x;
  const int qt  = 63 - (bid >> 5);   // descending work order
  const int bh  = bid & 31;
  const int h   = bh & 15;
  const int b   = bh >> 4;

  const size_t headoff = (size_t)h * 64;
  const size_t bbase   = (size_t)b * 4096;

  bf16x8 aq[2];
  {
    int row = qt*64 + w*16 + l15;
    const bf16* qp = Q + (bbase + row)*1024 + headoff + quad*8;
    aq[0] = *(const bf16x8*)(qp);
    aq[1] = *(const bf16x8*)(qp + 32);
  }

  short4v ones_s;
  {
    bf16x4 o1;
    #pragma unroll
    for (int j=0;j<4;j++) o1[j] = (bf16)1.0f;
    ones_s = __builtin_bit_cast(short4v, o1);
  }

  f32x4 acco[4];
  f32x4 accli;
  #pragma unroll
  for (int i=0;i<4;i++) acco[i] = (f32x4){0.f,0.f,0.f,0.f};
  accli = (f32x4){0.f,0.f,0.f,0.f};

  // ---- K staging geometry (byte offsets, hoisted once) ----
  const int kt_row = tid >> 2;
  const int kswz   = (kt_row & 7) << 4;
  const int ks_w0  = kt_row*128 + (((tid & 3)*32)      ^ kswz);
  const int ks_w1  = kt_row*128 + (((tid & 3)*32 + 16) ^ kswz);

  // ---- V staging geometry: thread owns (d=vd, t=vt0..vt0+15) of the tile ----
  const int vd  = tid >> 2;          // 0..63
  const int vt0 = (tid & 3) * 16;    // 0,16,32,48
  int vw[4];
  #pragma unroll
  for (int u=0;u<4;u++)
    vw[u] = vd*128 + (((vt0 + u*4)*2) ^ ((vd & 15) << 3));
  const bf16* vbase = Vt + ((size_t)(b*16 + h) * 64 + vd) * 4096 + vt0;

  // ---- read geometry (XOR decomposed into per-lane base + compile-time imm) ----
  // Ks read:  addr = tt*2048 + l15*128 + ((quad^(s7&3))<<4) + ((kk^(s7>>2))<<6)
  const int s7    = l15 & 7;
  const int ks_r0 = l15*128 + ((quad ^ (s7 & 3)) << 4) + ((s7 >> 2) << 6);
  const int ks_r1 = ks_r0 ^ 64;
  // Vt read:  addr = nt*2048 + l15*128 + ((quad^(l15&3))<<3) + ((tt^(l15>>2))<<5)
  const int vt_rbase = l15*128 + ((quad ^ (l15 & 3)) << 3) + ((l15 >> 2) << 5);
  int vt_r[4];
  #pragma unroll
  for (int tt=0;tt<4;tt++) vt_r[tt] = vt_rbase ^ (tt << 5);

  {
    const bf16* kp = Kp + (bbase + kt_row)*1024 + headoff + (tid & 3)*16;
    bf16x8 k0 = *(const bf16x8*)(kp);
    bf16x8 k1 = *(const bf16x8*)(kp + 8);
    *(bf16x8*)(KsB + ks_w0) = k0;
    *(bf16x8*)(KsB + ks_w1) = k1;
    bf16x8 v0 = *(const bf16x8*)(vbase);
    bf16x8 v1 = *(const bf16x8*)(vbase + 8);
    *(bf16x4*)(VtB + vw[0]) = __builtin_shufflevector(v0, v0, 0,1,2,3);
    *(bf16x4*)(VtB + vw[1]) = __builtin_shufflevector(v0, v0, 4,5,6,7);
    *(bf16x4*)(VtB + vw[2]) = __builtin_shufflevector(v1, v1, 0,1,2,3);
    *(bf16x4*)(VtB + vw[3]) = __builtin_shufflevector(v1, v1, 4,5,6,7);
  }
  __syncthreads();

  const bf16* kpref = Kp + (bbase + 64 + kt_row)*1024 + headoff + (tid & 3)*16;
  const bf16* vpref = vbase + 64;

  for (int kt = 0; kt <= qt; ++kt) {
    const int p = kt & 1;
    const bool pre = (kt < qt);

    bf16x8 kr0, kr1, vr0, vr1;
    if (pre) {
      kr0 = *(const bf16x8*)(kpref);
      kr1 = *(const bf16x8*)(kpref + 8);
      vr0 = *(const bf16x8*)(vpref);
      vr1 = *(const bf16x8*)(vpref + 8);
      kpref += 64*1024;
      vpref += 64;
    }

    const char* ksb = KsB + p*8192;
    const char* vtb = VtB + p*8192;

    f32x4 accs[4];
    #pragma unroll
    for (int i=0;i<4;i++) accs[i] = (f32x4){0.f,0.f,0.f,0.f};

    __builtin_amdgcn_s_setprio(1);
    #pragma unroll
    for (int kk=0;kk<2;kk++) {
      #pragma unroll
      for (int tt=0;tt<4;tt++) {
        bf16x8 ka = *(const bf16x8*)(ksb + (kk ? ks_r1 : ks_r0) + tt*2048);
        accs[tt] = MFMA16(ka, aq[kk], accs[tt]);
      }
    }
    __builtin_amdgcn_s_setprio(0);

    const bool diag = (kt == qt);
    short4v pts[4];
    #pragma unroll
    for (int tt=0;tt<4;tt++) {
      bf16x4 pb;
      #pragma unroll
      for (int r=0;r<4;r++) {
        float tv = fminf(accs[tt][r], 60.0f);          // accs already scaled (q pre-scaled)
        float pf = __builtin_amdgcn_exp2f(tv);
        if (diag && (tt*16 + quad*4 + r > w*16 + l15)) pf = 0.0f;
        pb[r] = (bf16)pf;
      }
      pts[tt] = __builtin_bit_cast(short4v, pb);
    }

    __builtin_amdgcn_s_setprio(1);
    #pragma unroll
    for (int nt=0;nt<4;nt++) {
      #pragma unroll
      for (int tt=0;tt<4;tt++) {
        bf16x4 va = *(const bf16x4*)(vtb + vt_r[tt] + nt*2048);
        acco[nt] = MFMAK16(__builtin_bit_cast(short4v, va), pts[tt], acco[nt]);
      }
    }
    #pragma unroll
    for (int tt=0;tt<4;tt++)
      accli = MFMAK16(ones_s, pts[tt], accli);
    __builtin_amdgcn_s_setprio(0);

    if (pre) {
      char* ksn = KsB + (p^1)*8192;
      char* vtn = VtB + (p^1)*8192;
      *(bf16x8*)(ksn + ks_w0) = kr0;
      *(bf16x8*)(ksn + ks_w1) = kr1;
      *(bf16x4*)(vtn + vw[0]) = __builtin_shufflevector(vr0, vr0, 0,1,2,3);
      *(bf16x4*)(vtn + vw[1]) = __builtin_shufflevector(vr0, vr0, 4,5,6,7);
      *(bf16x4*)(vtn + vw[2]) = __builtin_shufflevector(vr1, vr1, 0,1,2,3);
      *(bf16x4*)(vtn + vw[3]) = __builtin_shufflevector(vr1, vr1, 4,5,6,7);
      __syncthreads();
    }
  }

  {
    float inv = 1.0f / accli[0];
    int qrow = qt*64 + w*16 + l15;
    bf16* ob = O + (bbase + qrow)*1024 + headoff;
    #pragma unroll
    for (int nt=0;nt<4;nt++) {
      bf16x4 o;
      #pragma unroll
      for (int r=0;r<4;r++) o[r] = (bf16)(acco[nt][r] * inv);
      *(bf16x4*)(ob + nt*16 + quad*4) = o;
    }
  }
}

extern "C" void kernel_launch(void* const* d_in, const int* in_sizes, int n_in,
                              void* d_out, int out_size, void* d_ws, size_t ws_size,
                              hipStream_t stream) {
  const float* x  = (const float*)d_in[0];
  const float* Wq = (const float*)d_in[1];
  const float* bq = (const float*)d_in[2];
  const float* Wk = (const float*)d_in[3];
  const float* bk = (const float*)d_in[4];
  const float* Wv = (const float*)d_in[5];
  const float* bv = (const float*)d_in[6];
  const float* Wo = (const float*)d_in[7];
  const float* bo = (const float*)d_in[8];
  float* out = (float*)d_out;

  // ws (bf16 elems, 64 MB): q 8M | k 8M | v 8M (holds vT[b][h][d][t]) | xb 8M.
  // ao written in-place over q (block-exclusive slices). WtO reuses xb after gemm_qkv.
  // WtQKV (3M el) lives in d_out scratch (fully overwritten by the final GEMM).
  bf16* ws = (bf16*)d_ws;
  bf16* q  = ws;
  bf16* k  = q + (size_t)8192*1024;
  bf16* v  = k + (size_t)8192*1024;
  bf16* xb = v + (size_t)8192*1024;
  bf16* ao = q;                      // in-place
  bf16* WtQKV = (bf16*)d_out;        // scratch: dead before gemm_out writes d_out
  bf16* WtO   = xb;                  // xb dead after gemm_qkv

  tr_cast<<<dim3(16,16,3), dim3(64,16), 0, stream>>>(Wq, Wk, Wv, WtQKV);
  cast_x<<<4096, 256, 0, stream>>>(x, xb);
  gemm_qkv<<<dim3(24,64), 256, 0, stream>>>(xb, WtQKV, bq, bk, bv, q, k, v, 8192, 1024);
  tr_cast<<<dim3(16,16,1), dim3(64,16), 0, stream>>>(Wo, Wo, Wo, WtO);
  attn_fwd<<<2048, 256, 0, stream>>>(q, k, v, ao);
  gemm_out<<<dim3(8,64), 256, 0, stream>>>(ao, WtO, bo, out, 8192, 1024, 1024);
}